// Round 2
// baseline (12.990 us; speedup 1.0000x reference)
//
#include <hip/hip_runtime.h>

typedef float f32x2 __attribute__((ext_vector_type(2)));

// One wave per batch row, 4 waves/block, zero block barriers.
// Stage a_j = 1 + s_j for non-top-valid j (else -1e30) in this wave's own LDS
// segment; hinge = relu(a_j - s_i); the top-mask on i factors out of the j-sum.
__global__ __launch_bounds__(256) void prl_rows(
    const float* __restrict__ scores,
    const int* __restrict__ top_mask,
    const int* __restrict__ valid_mask,
    float* __restrict__ row_loss,
    unsigned int* __restrict__ row_cnt)
{
    __shared__ float a_sh[4][128];

    const int w    = threadIdx.x >> 6;
    const int lane = threadIdx.x & 63;
    const int row  = blockIdx.x * 4 + w;
    const size_t base = (size_t)row * 128;

    const float s0 = scores[base + lane];
    const float s1 = scores[base + lane + 64];
    const int tm0 = top_mask[base + lane],   tm1 = top_mask[base + lane + 64];
    const int vm0 = valid_mask[base + lane], vm1 = valid_mask[base + lane + 64];

    const bool top0 = (tm0 == 1), top1 = (tm1 == 1);
    const bool nt0  = (tm0 == 0) & (vm0 == 1);
    const bool nt1  = (tm1 == 0) & (vm1 == 1);

    // Margin folded in at stage time; masked j auto-zeroes through the relu.
    a_sh[w][lane]      = nt0 ? (1.0f + s0) : -1e30f;
    a_sh[w][lane + 64] = nt1 ? (1.0f + s1) : -1e30f;
    // Same-wave LDS write->read: lockstep wave + compiler lgkmcnt ordering;
    // wave_barrier pins the instruction order (no block barrier needed).
    __builtin_amdgcn_wave_barrier();

    f32x2 si;  si.x = s0;  si.y = s1;
    f32x2 acc; acc.x = 0.f; acc.y = 0.f;
    #pragma unroll
    for (int j = 0; j < 128; ++j) {
        const float aj = a_sh[w][j];          // broadcast read, conflict-free
        f32x2 d;
        d.x = fmaxf(aj - si.x, 0.f);
        d.y = fmaxf(aj - si.y, 0.f);
        acc += d;                              // v_pk_add_f32
    }

    float lane_loss = (top0 ? acc.x : 0.f) + (top1 ? acc.y : 0.f);
    #pragma unroll
    for (int o = 32; o > 0; o >>= 1)
        lane_loss += __shfl_xor(lane_loss, o, 64);

    // Exact pair count = (#top) * (#nontop-valid), via ballot popcounts.
    const unsigned long long bt0 = __ballot(top0), bt1 = __ballot(top1);
    const unsigned long long bn0 = __ballot(nt0),  bn1 = __ballot(nt1);

    if (lane == 0) {
        const unsigned t  = (unsigned)(__popcll(bt0) + __popcll(bt1));
        const unsigned nt = (unsigned)(__popcll(bn0) + __popcll(bn1));
        row_loss[row] = lane_loss;
        row_cnt[row]  = t * nt;
    }
}

// Single-wave finisher: 64 lanes x 16 float4/uint4 loads, all in flight at
// once, f64 tree reduce, one divide.
__global__ __launch_bounds__(64) void prl_final(
    const float* __restrict__ row_loss,
    const unsigned int* __restrict__ row_cnt,
    float* __restrict__ out,
    int rows)
{
    const int lane = threadIdx.x;
    double l = 0.0;
    unsigned long long c = 0;
    #pragma unroll
    for (int k = 0; k < 16; ++k) {
        const int idx = lane * 4 + k * 256;   // rows = 4096 = 16 * 256
        const float4 fl = *(const float4*)(row_loss + idx);
        const uint4  cc = *(const uint4*)(row_cnt + idx);
        l += (double)((fl.x + fl.y) + (fl.z + fl.w));
        c += (unsigned long long)(cc.x + cc.y + cc.z + cc.w);
    }
    #pragma unroll
    for (int o = 32; o > 0; o >>= 1) {
        l += __shfl_xor(l, o, 64);
        c += __shfl_xor(c, o, 64);
    }
    if (lane == 0)
        out[0] = (c > 0) ? (float)(l / (double)c) : (float)l;
}

extern "C" void kernel_launch(void* const* d_in, const int* in_sizes, int n_in,
                              void* d_out, int out_size, void* d_ws, size_t ws_size,
                              hipStream_t stream) {
    const float* scores = (const float*)d_in[0];
    const int*   top    = (const int*)d_in[1];
    const int*   valid  = (const int*)d_in[2];

    const int batch   = in_sizes[0] / 128;  // 4096 rows
    const int nblocks = batch / 4;          // 1024 blocks, 1 wave/row

    float*        row_loss = (float*)d_ws;
    unsigned int* row_cnt  = (unsigned int*)((char*)d_ws + (size_t)batch * sizeof(float));

    prl_rows<<<nblocks, 256, 0, stream>>>(scores, top, valid, row_loss, row_cnt);
    prl_final<<<1, 64, 0, stream>>>(row_loss, row_cnt, (float*)d_out, batch);
}